// Round 1
// baseline (2790.952 us; speedup 1.0000x reference)
//
#include <hip/hip_runtime.h>

#define DIM 64

// ---------------------------------------------------------------------------
// Phase 1: side[row] += ego[col] * val   (COO scatter, HW f32 atomics)
// 16 lanes per edge, float4 per lane -> coalesced 256B gather per edge.
// ---------------------------------------------------------------------------
__device__ __forceinline__ void atomAddF(float* p, float v) {
    __hip_atomic_fetch_add(p, v, __ATOMIC_RELAXED, __HIP_MEMORY_SCOPE_AGENT);
}

__global__ void scatter_k(const float* __restrict__ ego,
                          const int* __restrict__ erow,
                          const int* __restrict__ ecol,
                          const float* __restrict__ eval_,
                          float* __restrict__ side,
                          long long total16) {
    long long tid = (long long)blockIdx.x * blockDim.x + threadIdx.x;
    if (tid >= total16) return;
    const int e = (int)(tid >> 4);
    const int q = (int)(tid & 15);
    const int col = ecol[e];
    const int row = erow[e];
    const float v = eval_[e];
    const float4 g = *reinterpret_cast<const float4*>(ego + (size_t)col * DIM + q * 4);
    float* dst = side + (size_t)row * DIM + q * 4;
    atomAddF(dst + 0, g.x * v);
    atomAddF(dst + 1, g.y * v);
    atomAddF(dst + 2, g.z * v);
    atomAddF(dst + 3, g.w * v);
}

// ---------------------------------------------------------------------------
// Phase 2: out[n] = lrelu((e+s)@W1 + b1) + lrelu((e*s)@W2 + b2), in place:
// `out` holds side on entry. One wave per node; lane j owns output column j
// and keeps W1[*][j], W2[*][j] in 128 VGPRs (loaded once, grid-stride).
// x1/x2 are broadcast to the wave via a 512B private LDS slice.
// ---------------------------------------------------------------------------
__global__ __launch_bounds__(256) void mlp_k(const float* __restrict__ ego,
                                             const float* __restrict__ W1,
                                             const float* __restrict__ b1,
                                             const float* __restrict__ W2,
                                             const float* __restrict__ b2,
                                             float* out, int nNodes) {
    __shared__ __align__(16) float xsh[4][2][DIM];
    const int lane = threadIdx.x & 63;
    const int wid  = threadIdx.x >> 6;

    float w1[DIM], w2[DIM];
#pragma unroll
    for (int k = 0; k < DIM; ++k) {
        w1[k] = W1[k * DIM + lane];
        w2[k] = W2[k * DIM + lane];
    }
    const float bb1 = b1[lane];
    const float bb2 = b2[lane];

    const int waveId = blockIdx.x * 4 + wid;
    const int nWaves = gridDim.x * 4;

    for (int n = waveId; n < nNodes; n += nWaves) {
        const size_t base = (size_t)n * DIM + lane;
        const float e = ego[base];
        const float s = out[base];
        xsh[wid][0][lane] = e + s;
        xsh[wid][1][lane] = e * s;
        // same-wave DS ops complete in order; compiler inserts lgkmcnt waits
        float acc1 = bb1, acc2 = bb2;
#pragma unroll
        for (int k4 = 0; k4 < 16; ++k4) {
            const float4 a = *reinterpret_cast<const float4*>(&xsh[wid][0][k4 * 4]);
            const float4 m = *reinterpret_cast<const float4*>(&xsh[wid][1][k4 * 4]);
            acc1 = fmaf(a.x, w1[4 * k4 + 0], acc1);
            acc1 = fmaf(a.y, w1[4 * k4 + 1], acc1);
            acc1 = fmaf(a.z, w1[4 * k4 + 2], acc1);
            acc1 = fmaf(a.w, w1[4 * k4 + 3], acc1);
            acc2 = fmaf(m.x, w2[4 * k4 + 0], acc2);
            acc2 = fmaf(m.y, w2[4 * k4 + 1], acc2);
            acc2 = fmaf(m.z, w2[4 * k4 + 2], acc2);
            acc2 = fmaf(m.w, w2[4 * k4 + 3], acc2);
        }
        const float r1 = fmaxf(acc1, 0.f) + 0.01f * fminf(acc1, 0.f);
        const float r2 = fmaxf(acc2, 0.f) + 0.01f * fminf(acc2, 0.f);
        out[base] = r1 + r2;
    }
}

// ---------------------------------------------------------------------------
extern "C" void kernel_launch(void* const* d_in, const int* in_sizes, int n_in,
                              void* d_out, int out_size, void* d_ws, size_t ws_size,
                              hipStream_t stream) {
    const float* ego  = (const float*)d_in[0];
    const float* W1   = (const float*)d_in[1];
    const float* b1   = (const float*)d_in[2];
    const float* W2   = (const float*)d_in[3];
    const float* b2   = (const float*)d_in[4];
    const int*   erow = (const int*)d_in[5];
    const int*   ecol = (const int*)d_in[6];
    const float* ev   = (const float*)d_in[7];
    float* out = (float*)d_out;

    const int nNodes = in_sizes[0] / DIM;
    const int nEdges = in_sizes[5];

    // side accumulates directly in d_out (zeroed in-stream, graph-capture safe)
    hipMemsetAsync(out, 0, (size_t)out_size * sizeof(float), stream);

    const long long total16 = (long long)nEdges * 16;
    const int blocks = (int)((total16 + 255) / 256);
    scatter_k<<<blocks, 256, 0, stream>>>(ego, erow, ecol, ev, out, total16);

    mlp_k<<<1024, 256, 0, stream>>>(ego, W1, b1, W2, b2, out, nNodes);
}

// Round 2
// 757.818 us; speedup vs baseline: 3.6829x; 3.6829x over previous
//
#include <hip/hip_runtime.h>

#define DIM 64
#define SCAN_T 256
#define SCAN_E 8
#define SCAN_CHUNK (SCAN_T * SCAN_E)   // 2048 elements per scan block

// ---------------------------------------------------------------------------
// CSR build: histogram -> exclusive scan -> reorder (counting sort by row)
// ---------------------------------------------------------------------------
__global__ void hist_k(const int* __restrict__ erow, int* __restrict__ cnt, int E) {
    int e = blockIdx.x * blockDim.x + threadIdx.x;
    if (e < E) atomicAdd(&cnt[erow[e]], 1);
}

__global__ void scanA_k(const int* __restrict__ cnt, int* __restrict__ offs,
                        int* __restrict__ bsums, int N) {
    __shared__ int sh[SCAN_T];
    const int base = blockIdx.x * SCAN_CHUNK + threadIdx.x * SCAN_E;
    int v[SCAN_E];
    int s = 0;
#pragma unroll
    for (int j = 0; j < SCAN_E; ++j) {
        int idx = base + j;
        int c = (idx < N) ? cnt[idx] : 0;
        v[j] = s;
        s += c;
    }
    sh[threadIdx.x] = s;
    __syncthreads();
    // Hillis-Steele inclusive scan over 256 thread-sums
    for (int off = 1; off < SCAN_T; off <<= 1) {
        int t = (threadIdx.x >= off) ? sh[threadIdx.x - off] : 0;
        __syncthreads();
        sh[threadIdx.x] += t;
        __syncthreads();
    }
    const int excl = (threadIdx.x == 0) ? 0 : sh[threadIdx.x - 1];
    if (threadIdx.x == SCAN_T - 1) bsums[blockIdx.x] = sh[SCAN_T - 1];
#pragma unroll
    for (int j = 0; j < SCAN_E; ++j) {
        int idx = base + j;
        if (idx < N) offs[idx] = v[j] + excl;
    }
}

__global__ void scanB_k(int* __restrict__ bsums, int nb) {
    __shared__ int sh[1024];
    const int tid = threadIdx.x;
    if (tid < nb) sh[tid] = bsums[tid];
    __syncthreads();
    if (tid == 0) {
        int s = 0;
        for (int i = 0; i < nb; ++i) { int t = sh[i]; sh[i] = s; s += t; }
    }
    __syncthreads();
    if (tid < nb) bsums[tid] = sh[tid];
}

__global__ void scanC_k(int* __restrict__ offs, int* __restrict__ cursor,
                        const int* __restrict__ bsums, int N, int E) {
    const int i = blockIdx.x * blockDim.x + threadIdx.x;
    if (i < N) {
        int v = offs[i] + bsums[i / SCAN_CHUNK];
        offs[i] = v;
        cursor[i] = v;
    }
    if (i == 0) offs[N] = E;
}

__global__ void reorder_k(const int* __restrict__ erow, const int* __restrict__ ecol,
                          const float* __restrict__ ev, int* __restrict__ cursor,
                          int2* __restrict__ scv, int E) {
    int e = blockIdx.x * blockDim.x + threadIdx.x;
    if (e < E) {
        int r = erow[e];
        int pos = atomicAdd(&cursor[r], 1);
        scv[pos] = make_int2(ecol[e], __float_as_int(ev[e]));
    }
}

// ---------------------------------------------------------------------------
// Segment sum: one wave per row; lane = dim. Wave-uniform (col,val) load,
// coalesced 256B gather of ego[col], one plain 256B store per row.
// ---------------------------------------------------------------------------
__global__ __launch_bounds__(256) void segsum_k(const float* __restrict__ ego,
                                                const int* __restrict__ offs,
                                                const int2* __restrict__ scv,
                                                float* __restrict__ out, int N) {
    const int lane = threadIdx.x & 63;
    const int row = blockIdx.x * 4 + (threadIdx.x >> 6);
    if (row >= N) return;
    const int s = offs[row];
    const int t = offs[row + 1];
    float acc = 0.f;
    for (int e = s; e < t; ++e) {
        const int2 cv = scv[e];  // wave-uniform
        acc = fmaf(__int_as_float(cv.y), ego[(size_t)cv.x * DIM + lane], acc);
    }
    out[(size_t)row * DIM + lane] = acc;
}

// ---------------------------------------------------------------------------
// MLP epilogue (unchanged from round 1): out = lrelu((e+s)W1+b1)+lrelu((e*s)W2+b2)
// ---------------------------------------------------------------------------
__global__ __launch_bounds__(256) void mlp_k(const float* __restrict__ ego,
                                             const float* __restrict__ W1,
                                             const float* __restrict__ b1,
                                             const float* __restrict__ W2,
                                             const float* __restrict__ b2,
                                             float* out, int nNodes) {
    __shared__ __align__(16) float xsh[4][2][DIM];
    const int lane = threadIdx.x & 63;
    const int wid  = threadIdx.x >> 6;

    float w1[DIM], w2[DIM];
#pragma unroll
    for (int k = 0; k < DIM; ++k) {
        w1[k] = W1[k * DIM + lane];
        w2[k] = W2[k * DIM + lane];
    }
    const float bb1 = b1[lane];
    const float bb2 = b2[lane];

    const int waveId = blockIdx.x * 4 + wid;
    const int nWaves = gridDim.x * 4;

    for (int n = waveId; n < nNodes; n += nWaves) {
        const size_t base = (size_t)n * DIM + lane;
        const float e = ego[base];
        const float s = out[base];
        xsh[wid][0][lane] = e + s;
        xsh[wid][1][lane] = e * s;
        float acc1 = bb1, acc2 = bb2;
#pragma unroll
        for (int k4 = 0; k4 < 16; ++k4) {
            const float4 a = *reinterpret_cast<const float4*>(&xsh[wid][0][k4 * 4]);
            const float4 m = *reinterpret_cast<const float4*>(&xsh[wid][1][k4 * 4]);
            acc1 = fmaf(a.x, w1[4 * k4 + 0], acc1);
            acc1 = fmaf(a.y, w1[4 * k4 + 1], acc1);
            acc1 = fmaf(a.z, w1[4 * k4 + 2], acc1);
            acc1 = fmaf(a.w, w1[4 * k4 + 3], acc1);
            acc2 = fmaf(m.x, w2[4 * k4 + 0], acc2);
            acc2 = fmaf(m.y, w2[4 * k4 + 1], acc2);
            acc2 = fmaf(m.z, w2[4 * k4 + 2], acc2);
            acc2 = fmaf(m.w, w2[4 * k4 + 3], acc2);
        }
        const float r1 = fmaxf(acc1, 0.f) + 0.01f * fminf(acc1, 0.f);
        const float r2 = fmaxf(acc2, 0.f) + 0.01f * fminf(acc2, 0.f);
        out[base] = r1 + r2;
    }
}

// ---------------------------------------------------------------------------
// Fallback (round-1 atomic path) if workspace is too small
// ---------------------------------------------------------------------------
__device__ __forceinline__ void atomAddF(float* p, float v) {
    __hip_atomic_fetch_add(p, v, __ATOMIC_RELAXED, __HIP_MEMORY_SCOPE_AGENT);
}

__global__ void scatter_k(const float* __restrict__ ego,
                          const int* __restrict__ erow,
                          const int* __restrict__ ecol,
                          const float* __restrict__ eval_,
                          float* __restrict__ side,
                          long long total16) {
    long long tid = (long long)blockIdx.x * blockDim.x + threadIdx.x;
    if (tid >= total16) return;
    const int e = (int)(tid >> 4);
    const int q = (int)(tid & 15);
    const float4 g = *reinterpret_cast<const float4*>(ego + (size_t)ecol[e] * DIM + q * 4);
    const float v = eval_[e];
    float* dst = side + (size_t)erow[e] * DIM + q * 4;
    atomAddF(dst + 0, g.x * v);
    atomAddF(dst + 1, g.y * v);
    atomAddF(dst + 2, g.z * v);
    atomAddF(dst + 3, g.w * v);
}

// ---------------------------------------------------------------------------
extern "C" void kernel_launch(void* const* d_in, const int* in_sizes, int n_in,
                              void* d_out, int out_size, void* d_ws, size_t ws_size,
                              hipStream_t stream) {
    const float* ego  = (const float*)d_in[0];
    const float* W1   = (const float*)d_in[1];
    const float* b1   = (const float*)d_in[2];
    const float* W2   = (const float*)d_in[3];
    const float* b2   = (const float*)d_in[4];
    const int*   erow = (const int*)d_in[5];
    const int*   ecol = (const int*)d_in[6];
    const float* ev   = (const float*)d_in[7];
    float* out = (float*)d_out;

    const int N = in_sizes[0] / DIM;
    const int E = in_sizes[5];

    // ---- workspace layout (ints), 256B-aligned regions ----
    auto align256 = [](size_t x) { return (x + 63) & ~(size_t)63; };  // in ints (64*4=256B)
    size_t o_cnt    = 0;
    size_t o_offs   = align256(o_cnt + N);
    size_t o_cursor = align256(o_offs + N + 1);
    size_t o_bsums  = align256(o_cursor + N);
    size_t o_scv    = align256(o_bsums + 1024);
    size_t need     = (o_scv + (size_t)2 * E) * sizeof(int);

    if (ws_size < need) {
        // fallback: atomic scatter path
        hipMemsetAsync(out, 0, (size_t)out_size * sizeof(float), stream);
        const long long total16 = (long long)E * 16;
        scatter_k<<<(int)((total16 + 255) / 256), 256, 0, stream>>>(ego, erow, ecol, ev, out, total16);
        mlp_k<<<1024, 256, 0, stream>>>(ego, W1, b1, W2, b2, out, N);
        return;
    }

    int* ws = (int*)d_ws;
    int* cnt    = ws + o_cnt;
    int* offs   = ws + o_offs;
    int* cursor = ws + o_cursor;
    int* bsums  = ws + o_bsums;
    int2* scv   = (int2*)(ws + o_scv);

    const int nb = (N + SCAN_CHUNK - 1) / SCAN_CHUNK;

    hipMemsetAsync(cnt, 0, (size_t)N * sizeof(int), stream);
    hist_k<<<(E + 255) / 256, 256, 0, stream>>>(erow, cnt, E);
    scanA_k<<<nb, SCAN_T, 0, stream>>>(cnt, offs, bsums, N);
    scanB_k<<<1, 1024, 0, stream>>>(bsums, nb);
    scanC_k<<<(N + 255) / 256, 256, 0, stream>>>(offs, cursor, bsums, N, E);
    reorder_k<<<(E + 255) / 256, 256, 0, stream>>>(erow, ecol, ev, cursor, scv, E);
    segsum_k<<<(N + 3) / 4, 256, 0, stream>>>(ego, offs, scv, out, N);
    mlp_k<<<1024, 256, 0, stream>>>(ego, W1, b1, W2, b2, out, N);
}

// Round 3
// 715.879 us; speedup vs baseline: 3.8986x; 1.0586x over previous
//
#include <hip/hip_runtime.h>

#define DIM 64
#define SCAN_T 256
#define SCAN_E 8
#define SCAN_CHUNK (SCAN_T * SCAN_E)   // 2048 elements per scan block

// ---------------------------------------------------------------------------
// CSR build: histogram -> exclusive scan -> reorder (counting sort by row)
// ---------------------------------------------------------------------------
__global__ void hist_k(const int* __restrict__ erow, int* __restrict__ cnt, int E) {
    const int e4 = (blockIdx.x * blockDim.x + threadIdx.x) * 4;
    if (e4 + 3 < E) {
        const int4 r = *reinterpret_cast<const int4*>(erow + e4);
        atomicAdd(&cnt[r.x], 1);
        atomicAdd(&cnt[r.y], 1);
        atomicAdd(&cnt[r.z], 1);
        atomicAdd(&cnt[r.w], 1);
    } else {
        for (int e = e4; e < E; ++e) atomicAdd(&cnt[erow[e]], 1);
    }
}

__global__ void scanA_k(const int* __restrict__ cnt, int* __restrict__ offs,
                        int* __restrict__ bsums, int N) {
    __shared__ int sh[SCAN_T];
    const int base = blockIdx.x * SCAN_CHUNK + threadIdx.x * SCAN_E;
    int v[SCAN_E];
    int s = 0;
#pragma unroll
    for (int j = 0; j < SCAN_E; ++j) {
        int idx = base + j;
        int c = (idx < N) ? cnt[idx] : 0;
        v[j] = s;
        s += c;
    }
    sh[threadIdx.x] = s;
    __syncthreads();
    for (int off = 1; off < SCAN_T; off <<= 1) {
        int t = (threadIdx.x >= off) ? sh[threadIdx.x - off] : 0;
        __syncthreads();
        sh[threadIdx.x] += t;
        __syncthreads();
    }
    const int excl = (threadIdx.x == 0) ? 0 : sh[threadIdx.x - 1];
    if (threadIdx.x == SCAN_T - 1) bsums[blockIdx.x] = sh[SCAN_T - 1];
#pragma unroll
    for (int j = 0; j < SCAN_E; ++j) {
        int idx = base + j;
        if (idx < N) offs[idx] = v[j] + excl;
    }
}

__global__ void scanB_k(int* __restrict__ bsums, int nb) {
    __shared__ int sh[1024];
    const int tid = threadIdx.x;
    if (tid < nb) sh[tid] = bsums[tid];
    __syncthreads();
    if (tid == 0) {
        int s = 0;
        for (int i = 0; i < nb; ++i) { int t = sh[i]; sh[i] = s; s += t; }
    }
    __syncthreads();
    if (tid < nb) bsums[tid] = sh[tid];
}

__global__ void scanC_k(int* __restrict__ offs, int* __restrict__ cursor,
                        const int* __restrict__ bsums, int N, int E) {
    const int i = blockIdx.x * blockDim.x + threadIdx.x;
    if (i < N) {
        int v = offs[i] + bsums[i / SCAN_CHUNK];
        offs[i] = v;
        cursor[i] = v;
    }
    if (i == 0) offs[N] = E;
}

__global__ void reorder_k(const int* __restrict__ erow, const int* __restrict__ ecol,
                          const float* __restrict__ ev, int* __restrict__ cursor,
                          int2* __restrict__ scv, int E) {
    const int e4 = (blockIdx.x * blockDim.x + threadIdx.x) * 4;
    if (e4 + 3 < E) {
        const int4   r = *reinterpret_cast<const int4*>(erow + e4);
        const int4   c = *reinterpret_cast<const int4*>(ecol + e4);
        const float4 v = *reinterpret_cast<const float4*>(ev + e4);
        int p;
        p = atomicAdd(&cursor[r.x], 1); scv[p] = make_int2(c.x, __float_as_int(v.x));
        p = atomicAdd(&cursor[r.y], 1); scv[p] = make_int2(c.y, __float_as_int(v.y));
        p = atomicAdd(&cursor[r.z], 1); scv[p] = make_int2(c.z, __float_as_int(v.z));
        p = atomicAdd(&cursor[r.w], 1); scv[p] = make_int2(c.w, __float_as_int(v.w));
    } else {
        for (int e = e4; e < E; ++e) {
            int p = atomicAdd(&cursor[erow[e]], 1);
            scv[p] = make_int2(ecol[e], __float_as_int(ev[e]));
        }
    }
}

// ---------------------------------------------------------------------------
// Fused segment-sum + bi-interaction MLP. One wave per row (contiguous span
// per persistent wave). lane = dim. Edge (col,val) pairs are loaded 64-at-a-
// time coalesced and broadcast via __shfl, so the 256B ego-gathers are
// independent and 8-deep in flight. W1/W2 columns live in 128 VGPRs.
// ---------------------------------------------------------------------------
__device__ __forceinline__ float lrelu(float x) {
    return fmaxf(x, 0.f) + 0.01f * fminf(x, 0.f);
}

__global__ __launch_bounds__(256, 2) void fused_k(const float* __restrict__ ego,
                                                  const float* __restrict__ W1,
                                                  const float* __restrict__ b1,
                                                  const float* __restrict__ W2,
                                                  const float* __restrict__ b2,
                                                  const int* __restrict__ offs,
                                                  const int2* __restrict__ scv,
                                                  float* __restrict__ out,
                                                  int N, int rowsPerWave) {
    __shared__ __align__(16) float xsh[4][2][DIM];
    const int lane = threadIdx.x & 63;
    const int wid  = threadIdx.x >> 6;

    float w1[DIM], w2[DIM];
#pragma unroll
    for (int k = 0; k < DIM; ++k) {
        w1[k] = W1[k * DIM + lane];
        w2[k] = W2[k * DIM + lane];
    }
    const float bb1 = b1[lane];
    const float bb2 = b2[lane];

    const int waveId = blockIdx.x * 4 + wid;
    const int r0 = waveId * rowsPerWave;
    const int r1 = min(N, r0 + rowsPerWave);

    for (int row = r0; row < r1; ++row) {
        const int s = offs[row];
        const int t = offs[row + 1];
        float acc = 0.f;
        for (int base = s; base < t; base += 64) {
            const int m = min(64, t - base);
            const int2 cv = (lane < m) ? scv[base + lane] : make_int2(0, 0);
            int j = 0;
            for (; j + 8 <= m; j += 8) {
                const int c0 = __shfl(cv.x, j + 0), c1 = __shfl(cv.x, j + 1);
                const int c2 = __shfl(cv.x, j + 2), c3 = __shfl(cv.x, j + 3);
                const int c4 = __shfl(cv.x, j + 4), c5 = __shfl(cv.x, j + 5);
                const int c6 = __shfl(cv.x, j + 6), c7 = __shfl(cv.x, j + 7);
                const float v0 = __int_as_float(__shfl(cv.y, j + 0));
                const float v1 = __int_as_float(__shfl(cv.y, j + 1));
                const float v2 = __int_as_float(__shfl(cv.y, j + 2));
                const float v3 = __int_as_float(__shfl(cv.y, j + 3));
                const float v4 = __int_as_float(__shfl(cv.y, j + 4));
                const float v5 = __int_as_float(__shfl(cv.y, j + 5));
                const float v6 = __int_as_float(__shfl(cv.y, j + 6));
                const float v7 = __int_as_float(__shfl(cv.y, j + 7));
                const float g0 = ego[c0 * DIM + lane];
                const float g1 = ego[c1 * DIM + lane];
                const float g2 = ego[c2 * DIM + lane];
                const float g3 = ego[c3 * DIM + lane];
                const float g4 = ego[c4 * DIM + lane];
                const float g5 = ego[c5 * DIM + lane];
                const float g6 = ego[c6 * DIM + lane];
                const float g7 = ego[c7 * DIM + lane];
                acc = fmaf(v0, g0, acc); acc = fmaf(v1, g1, acc);
                acc = fmaf(v2, g2, acc); acc = fmaf(v3, g3, acc);
                acc = fmaf(v4, g4, acc); acc = fmaf(v5, g5, acc);
                acc = fmaf(v6, g6, acc); acc = fmaf(v7, g7, acc);
            }
            for (; j < m; ++j) {
                const int   c = __shfl(cv.x, j);
                const float v = __int_as_float(__shfl(cv.y, j));
                acc = fmaf(v, ego[c * DIM + lane], acc);
            }
        }
        // ---- fused bi-interaction MLP ----
        const int base = row * DIM + lane;
        const float e = ego[base];
        xsh[wid][0][lane] = e + acc;
        xsh[wid][1][lane] = e * acc;
        float a1 = bb1, a2 = bb2;
#pragma unroll
        for (int k4 = 0; k4 < 16; ++k4) {
            const float4 xa = *reinterpret_cast<const float4*>(&xsh[wid][0][k4 * 4]);
            const float4 xm = *reinterpret_cast<const float4*>(&xsh[wid][1][k4 * 4]);
            a1 = fmaf(xa.x, w1[4 * k4 + 0], a1);
            a1 = fmaf(xa.y, w1[4 * k4 + 1], a1);
            a1 = fmaf(xa.z, w1[4 * k4 + 2], a1);
            a1 = fmaf(xa.w, w1[4 * k4 + 3], a1);
            a2 = fmaf(xm.x, w2[4 * k4 + 0], a2);
            a2 = fmaf(xm.y, w2[4 * k4 + 1], a2);
            a2 = fmaf(xm.z, w2[4 * k4 + 2], a2);
            a2 = fmaf(xm.w, w2[4 * k4 + 3], a2);
        }
        out[base] = lrelu(a1) + lrelu(a2);
    }
}

// ---------------------------------------------------------------------------
// Fallback (atomic path) + standalone MLP, if workspace too small
// ---------------------------------------------------------------------------
__device__ __forceinline__ void atomAddF(float* p, float v) {
    __hip_atomic_fetch_add(p, v, __ATOMIC_RELAXED, __HIP_MEMORY_SCOPE_AGENT);
}

__global__ void scatter_k(const float* __restrict__ ego,
                          const int* __restrict__ erow,
                          const int* __restrict__ ecol,
                          const float* __restrict__ eval_,
                          float* __restrict__ side,
                          long long total16) {
    long long tid = (long long)blockIdx.x * blockDim.x + threadIdx.x;
    if (tid >= total16) return;
    const int e = (int)(tid >> 4);
    const int q = (int)(tid & 15);
    const float4 g = *reinterpret_cast<const float4*>(ego + (size_t)ecol[e] * DIM + q * 4);
    const float v = eval_[e];
    float* dst = side + (size_t)erow[e] * DIM + q * 4;
    atomAddF(dst + 0, g.x * v);
    atomAddF(dst + 1, g.y * v);
    atomAddF(dst + 2, g.z * v);
    atomAddF(dst + 3, g.w * v);
}

__global__ __launch_bounds__(256) void mlp_k(const float* __restrict__ ego,
                                             const float* __restrict__ W1,
                                             const float* __restrict__ b1,
                                             const float* __restrict__ W2,
                                             const float* __restrict__ b2,
                                             float* out, int nNodes) {
    __shared__ __align__(16) float xsh[4][2][DIM];
    const int lane = threadIdx.x & 63;
    const int wid  = threadIdx.x >> 6;
    float w1[DIM], w2[DIM];
#pragma unroll
    for (int k = 0; k < DIM; ++k) {
        w1[k] = W1[k * DIM + lane];
        w2[k] = W2[k * DIM + lane];
    }
    const float bb1 = b1[lane];
    const float bb2 = b2[lane];
    const int waveId = blockIdx.x * 4 + wid;
    const int nWaves = gridDim.x * 4;
    for (int n = waveId; n < nNodes; n += nWaves) {
        const size_t base = (size_t)n * DIM + lane;
        const float e = ego[base];
        const float s = out[base];
        xsh[wid][0][lane] = e + s;
        xsh[wid][1][lane] = e * s;
        float acc1 = bb1, acc2 = bb2;
#pragma unroll
        for (int k4 = 0; k4 < 16; ++k4) {
            const float4 a = *reinterpret_cast<const float4*>(&xsh[wid][0][k4 * 4]);
            const float4 m = *reinterpret_cast<const float4*>(&xsh[wid][1][k4 * 4]);
            acc1 = fmaf(a.x, w1[4 * k4 + 0], acc1);
            acc1 = fmaf(a.y, w1[4 * k4 + 1], acc1);
            acc1 = fmaf(a.z, w1[4 * k4 + 2], acc1);
            acc1 = fmaf(a.w, w1[4 * k4 + 3], acc1);
            acc2 = fmaf(m.x, w2[4 * k4 + 0], acc2);
            acc2 = fmaf(m.y, w2[4 * k4 + 1], acc2);
            acc2 = fmaf(m.z, w2[4 * k4 + 2], acc2);
            ac2 :;
            acc2 = fmaf(m.w, w2[4 * k4 + 3], acc2);
        }
        const float r1 = fmaxf(acc1, 0.f) + 0.01f * fminf(acc1, 0.f);
        const float r2 = fmaxf(acc2, 0.f) + 0.01f * fminf(acc2, 0.f);
        out[base] = r1 + r2;
    }
}

// ---------------------------------------------------------------------------
extern "C" void kernel_launch(void* const* d_in, const int* in_sizes, int n_in,
                              void* d_out, int out_size, void* d_ws, size_t ws_size,
                              hipStream_t stream) {
    const float* ego  = (const float*)d_in[0];
    const float* W1   = (const float*)d_in[1];
    const float* b1   = (const float*)d_in[2];
    const float* W2   = (const float*)d_in[3];
    const float* b2   = (const float*)d_in[4];
    const int*   erow = (const int*)d_in[5];
    const int*   ecol = (const int*)d_in[6];
    const float* ev   = (const float*)d_in[7];
    float* out = (float*)d_out;

    const int N = in_sizes[0] / DIM;
    const int E = in_sizes[5];

    auto align256 = [](size_t x) { return (x + 63) & ~(size_t)63; };  // ints
    size_t o_cnt    = 0;
    size_t o_offs   = align256(o_cnt + N);
    size_t o_cursor = align256(o_offs + N + 1);
    size_t o_bsums  = align256(o_cursor + N);
    size_t o_scv    = align256(o_bsums + 1024);
    size_t need     = (o_scv + (size_t)2 * E) * sizeof(int);

    if (ws_size < need) {
        hipMemsetAsync(out, 0, (size_t)out_size * sizeof(float), stream);
        const long long total16 = (long long)E * 16;
        scatter_k<<<(int)((total16 + 255) / 256), 256, 0, stream>>>(ego, erow, ecol, ev, out, total16);
        mlp_k<<<1024, 256, 0, stream>>>(ego, W1, b1, W2, b2, out, N);
        return;
    }

    int* ws = (int*)d_ws;
    int* cnt    = ws + o_cnt;
    int* offs   = ws + o_offs;
    int* cursor = ws + o_cursor;
    int* bsums  = ws + o_bsums;
    int2* scv   = (int2*)(ws + o_scv);

    const int nb = (N + SCAN_CHUNK - 1) / SCAN_CHUNK;

    hipMemsetAsync(cnt, 0, (size_t)N * sizeof(int), stream);
    hist_k<<<(E / 4 + 255) / 256, 256, 0, stream>>>(erow, cnt, E);
    scanA_k<<<nb, SCAN_T, 0, stream>>>(cnt, offs, bsums, N);
    scanB_k<<<1, 1024, 0, stream>>>(bsums, nb);
    scanC_k<<<(N + 255) / 256, 256, 0, stream>>>(offs, cursor, bsums, N, E);
    reorder_k<<<(E / 4 + 255) / 256, 256, 0, stream>>>(erow, ecol, ev, cursor, scv, E);

    const int nBlocks = 1024;
    const int nWaves = nBlocks * 4;
    const int rowsPerWave = (N + nWaves - 1) / nWaves;
    fused_k<<<nBlocks, 256, 0, stream>>>(ego, W1, b1, W2, b2, offs, scv, out, N, rowsPerWave);
}